// Round 4
// baseline (1362.825 us; speedup 1.0000x reference)
//
#include <hip/hip_runtime.h>

// APPNP: h0 = relu(x@W1+b1)@W2+b2 ; 10x: h = 0.9*(D^-1/2 A_sl D^-1/2 h) + 0.1*h0
// R2: dst-bucket bin + LDS CSR build; hs = dinv*h fp16; pure-sum gather.
// R3: mlp: padded h1s (stride 264), dbuf pipelined phase-1, W2 frags direct from
//     global, 50 KB LDS -> 3 blocks/CU. prop: degree-sorted perm order (kills
//     wave divergence), 4x edge unroll, h0 in fp16.

typedef unsigned short u16;
typedef unsigned int   u32;
typedef __bf16    bfx8  __attribute__((ext_vector_type(8)));
typedef _Float16  h16x8 __attribute__((ext_vector_type(8)));
typedef float     f32x4 __attribute__((ext_vector_type(4)));

#define CAP 4096      // per-bucket edge capacity (mean 2048)
#define EPB 16384     // edges per binscat block
#define NBMAX 1792    // bucket count upper bound for LDS arrays

__device__ __forceinline__ u16 f2bf(float f) {
    u32 u = __float_as_uint(f);
    u += 0x7fffu + ((u >> 16) & 1u);   // RNE
    return (u16)(u >> 16);
}

// ---------------- build pass 1: bin edges by dst bucket ----------------

__global__ __launch_bounds__(256) void binscat_kernel(
        const int* __restrict__ src, const int* __restrict__ dst,
        int* __restrict__ gcur, u32* __restrict__ binned, int E, int NB) {
    __shared__ int cnt[NBMAX];
    int tid = threadIdx.x;
#pragma unroll
    for (int j = 0; j < NBMAX / 256; ++j) cnt[tid + j * 256] = 0;
    __syncthreads();
    int e0 = blockIdx.x * EPB;
    for (int r = 0; r < EPB / 256; ++r) {
        int i = e0 + r * 256 + tid;
        if (i < E) atomicAdd(&cnt[dst[i] >> 6], 1);
    }
    __syncthreads();
    for (int j = 0; j < NBMAX / 256; ++j) {
        int b = tid + j * 256;
        if (b < NB) {
            int c = cnt[b];
            cnt[b] = (c > 0) ? atomicAdd(&gcur[b], c) : 0;
        }
    }
    __syncthreads();
    for (int r = 0; r < EPB / 256; ++r) {
        int i = e0 + r * 256 + tid;
        if (i < E) {
            int d = dst[i];
            int s = src[i];
            int bb = d >> 6;
            int p = atomicAdd(&cnt[bb], 1);
            if (p < CAP) binned[(size_t)bb * CAP + p] = ((u32)(d & 63) << 17) | (u32)s;
        }
    }
}

// ---------------- build pass 2: exclusive scan of bucket counts ----------------

__global__ __launch_bounds__(256) void bucket_scan_kernel(
        const int* __restrict__ gcur, int* __restrict__ bbase,
        int* __restrict__ rp, int N, int NB) {
    __shared__ int tsum[256];
    int tid = threadIdx.x;
    int loc[7];
    int run = 0;
#pragma unroll
    for (int j = 0; j < 7; ++j) {
        int b = tid * 7 + j;
        int v = 0;
        if (b < NB) { v = gcur[b]; if (v > CAP) v = CAP; }
        loc[j] = run;
        run += v;
    }
    tsum[tid] = run;
    __syncthreads();
    for (int off = 1; off < 256; off <<= 1) {
        int t = (tid >= off) ? tsum[tid - off] : 0;
        __syncthreads();
        tsum[tid] += t;
        __syncthreads();
    }
    int texcl = tsum[tid] - run;
#pragma unroll
    for (int j = 0; j < 7; ++j) {
        int b = tid * 7 + j;
        if (b < NB) bbase[b] = texcl + loc[j];
    }
    if (tid == 255) rp[N] = tsum[255];   // == E
}

// ---------------- build pass 3: per-bucket CSR in LDS (+rp,+dinv,+deg hist) ----------------

__global__ __launch_bounds__(256) void buildcsr_kernel(
        const u32* __restrict__ binned, const int* __restrict__ gcur,
        const int* __restrict__ bbase, int* __restrict__ rp,
        float* __restrict__ dinv, int* __restrict__ csr,
        int* __restrict__ dhist, int N) {
    __shared__ u32 eb[CAP];
    __shared__ int lcsr[CAP];
    __shared__ int ncnt[64];
    __shared__ int lcur[64];
    int b = blockIdx.x;
    int tid = threadIdx.x;
    int cnt = gcur[b]; if (cnt > CAP) cnt = CAP;
    int base = bbase[b];
    if (tid < 64) ncnt[tid] = 0;
    __syncthreads();
    for (int idx = tid; idx < cnt; idx += 256) {
        u32 v = binned[(size_t)b * CAP + idx];
        eb[idx] = v;
        atomicAdd(&ncnt[v >> 17], 1);
    }
    __syncthreads();
    if (tid < 64) {
        int c = ncnt[tid];
        int s = c;
#pragma unroll
        for (int off = 1; off < 64; off <<= 1) {
            int t = __shfl_up(s, off);
            if (tid >= off) s += t;
        }
        int excl = s - c;
        lcur[tid] = excl;
        int node = b * 64 + tid;
        if (node < N) {
            rp[node] = base + excl;
            dinv[node] = rsqrtf(1.0f + (float)c);
            int dg = c > 127 ? 127 : c;
            atomicAdd(&dhist[dg], 1);
        }
    }
    __syncthreads();
    for (int idx = tid; idx < cnt; idx += 256) {
        u32 v = eb[idx];
        int p = atomicAdd(&lcur[v >> 17], 1);
        lcsr[p] = (int)(v & 0x1FFFFu);
    }
    __syncthreads();
    for (int idx = tid; idx < cnt; idx += 256)
        csr[base + idx] = lcsr[idx];
}

// ---------------- degree-order permutation ----------------

__global__ void dscan_kernel(const int* __restrict__ dhist, int* __restrict__ dcur) {
    __shared__ int s[128];
    int tid = threadIdx.x;   // 128 threads
    int v = dhist[tid];
    s[tid] = v;
    __syncthreads();
    for (int off = 1; off < 128; off <<= 1) {
        int t = (tid >= off) ? s[tid - off] : 0;
        __syncthreads();
        s[tid] += t;
        __syncthreads();
    }
    dcur[tid] = s[tid] - v;   // exclusive
}

__global__ __launch_bounds__(256) void dplace_kernel(
        const int* __restrict__ rp, int* __restrict__ dcur,
        int* __restrict__ perm, int N) {
    __shared__ int cnt[128];
    __shared__ int base[128];
    int tid = threadIdx.x;
    if (tid < 128) cnt[tid] = 0;
    __syncthreads();
    int i = blockIdx.x * 256 + tid;
    int deg = 0, lpos = 0;
    bool valid = i < N;
    if (valid) {
        deg = rp[i + 1] - rp[i];
        if (deg > 127) deg = 127;
        lpos = atomicAdd(&cnt[deg], 1);
    }
    __syncthreads();
    if (tid < 128) base[tid] = cnt[tid] ? atomicAdd(&dcur[tid], cnt[tid]) : 0;
    __syncthreads();
    if (valid) perm[base[deg] + lpos] = i;
}

// ---------------- weight pre-transpose to bf16 ----------------

__global__ void prepw1_kernel(const float* __restrict__ W1, u16* __restrict__ W1t) {
    int id = blockIdx.x * 256 + threadIdx.x;   // id = k*256 + n
    int k = id >> 8, n = id & 255;
    W1t[n * 512 + k] = f2bf(W1[id]);
}

__global__ void prepw2_kernel(const float* __restrict__ W2, u16* __restrict__ W2t) {
    int id = blockIdx.x * 256 + threadIdx.x;   // id = k*64 + n
    int k = id >> 6, n = id & 63;
    W2t[n * 256 + k] = f2bf(W2[id]);
}

// ---------------- fused MLP -> h0h (fp16) and hs = dinv*h0 (fp16) ----------------
// 64 rows/block, 4 waves. Phase1 dbuf pipelined BK=32; phase2: h1s padded, W2 frags global.
// mfma_f32_16x16x32_bf16: A[m=lr][k=lq*8+j]; B[n=lr][k=lq*8+j]; D col=lr, row=lq*4+r

__global__ __launch_bounds__(256) void mlp_kernel(
        const float* __restrict__ x, const u16* __restrict__ W1t,
        const float* __restrict__ b1, const u16* __restrict__ W2t,
        const float* __restrict__ b2, const float* __restrict__ dinv,
        _Float16* __restrict__ h0h, _Float16* __restrict__ hA, int N) {
    // LDS map: xs[2] @ 0 (2*5120), w1s[2] @ 10240 (2*20480) -> 51200 total.
    // phase2: h1s @ 0: 64*264*2 = 33792 (overlays phase1, after final barrier)
    __shared__ __align__(16) char lds[51200];

    const int tid  = threadIdx.x;
    const int wave = tid >> 6;
    const int lane = tid & 63;
    const int lq   = lane >> 4;
    const int lr   = lane & 15;
    const int blockRow = blockIdx.x * 64;

    const int sr = tid >> 2;           // x stage: row 0..63
    const int sc = (tid & 3) << 3;     // x stage: col 0..31 step 8

    float xv[8];
    uint4 wv[4];
    auto load_tile = [&](int ks) {
        int kk = ks * 32;
        int gr = blockRow + sr;
        if (gr < N) {
            const float* p = x + (size_t)gr * 512 + kk + sc;
            float4 a0 = *(const float4*)p;
            float4 a1 = *(const float4*)(p + 4);
            xv[0]=a0.x; xv[1]=a0.y; xv[2]=a0.z; xv[3]=a0.w;
            xv[4]=a1.x; xv[5]=a1.y; xv[6]=a1.z; xv[7]=a1.w;
        } else {
#pragma unroll
            for (int j = 0; j < 8; ++j) xv[j] = 0.f;
        }
        const uint4* q = (const uint4*)(W1t + (size_t)tid * 512 + kk);
        wv[0]=q[0]; wv[1]=q[1]; wv[2]=q[2]; wv[3]=q[3];
    };
    auto store_tile = [&](int buf) {
        u16* xsb = (u16*)(lds + buf * 5120);
        u32 pk[4];
#pragma unroll
        for (int j = 0; j < 4; ++j)
            pk[j] = (u32)f2bf(xv[2*j]) | ((u32)f2bf(xv[2*j+1]) << 16);
        *(uint4*)&xsb[sr * 40 + sc] = make_uint4(pk[0], pk[1], pk[2], pk[3]);
        u16* w1b = (u16*)(lds + 10240 + buf * 20480);
        uint4* qq = (uint4*)&w1b[tid * 40];
        qq[0]=wv[0]; qq[1]=wv[1]; qq[2]=wv[2]; qq[3]=wv[3];
    };

    f32x4 acc[4][4];
#pragma unroll
    for (int a = 0; a < 4; ++a)
#pragma unroll
        for (int b = 0; b < 4; ++b) acc[a][b] = (f32x4){0.f, 0.f, 0.f, 0.f};

    // ---- GEMM1: K=512, BK=32, double-buffered pipeline ----
    load_tile(0);
    store_tile(0);
    __syncthreads();
    for (int ks = 0; ks < 16; ++ks) {
        int buf = ks & 1;
        if (ks < 15) load_tile(ks + 1);          // global loads in flight over MFMA
        const u16* xsb = (const u16*)(lds + buf * 5120);
        const u16* w1b = (const u16*)(lds + 10240 + buf * 20480);
        bfx8 fa[4], fb[4];
#pragma unroll
        for (int mt = 0; mt < 4; ++mt)
            fa[mt] = *(const bfx8*)&xsb[(mt * 16 + lr) * 40 + lq * 8];
#pragma unroll
        for (int nt = 0; nt < 4; ++nt)
            fb[nt] = *(const bfx8*)&w1b[(wave * 64 + nt * 16 + lr) * 40 + lq * 8];
#pragma unroll
        for (int mt = 0; mt < 4; ++mt)
#pragma unroll
            for (int nt = 0; nt < 4; ++nt)
                acc[mt][nt] = __builtin_amdgcn_mfma_f32_16x16x32_bf16(
                    fa[mt], fb[nt], acc[mt][nt], 0, 0, 0);
        __syncthreads();
        if (ks < 15) store_tile(buf ^ 1);
        __syncthreads();
    }

    // ---- epilogue1: bias+relu -> h1s bf16, stride 264 (bank-conflict-free-ish) ----
    u16* h1s = (u16*)lds;
#pragma unroll
    for (int nt = 0; nt < 4; ++nt) {
        int col = wave * 64 + nt * 16 + lr;
        float bb = b1[col];
#pragma unroll
        for (int mt = 0; mt < 4; ++mt)
#pragma unroll
            for (int r = 0; r < 4; ++r) {
                int row = mt * 16 + lq * 4 + r;
                float v = acc[mt][nt][r] + bb;
                v = v > 0.f ? v : 0.f;
                h1s[row * 264 + col] = f2bf(v);
            }
    }
    __syncthreads();

    // ---- GEMM2: wave w -> rows [16w,16w+16), cols 0..63, K=256; W2 frags from global ----
    f32x4 acc2[4];
#pragma unroll
    for (int a = 0; a < 4; ++a) acc2[a] = (f32x4){0.f, 0.f, 0.f, 0.f};
    for (int kk = 0; kk < 256; kk += 32) {
        bfx8 a = *(const bfx8*)&h1s[(wave * 16 + lr) * 264 + kk + lq * 8];
#pragma unroll
        for (int nt = 0; nt < 4; ++nt) {
            bfx8 b = *(const bfx8*)(W2t + (nt * 16 + lr) * 256 + kk + lq * 8);
            acc2[nt] = __builtin_amdgcn_mfma_f32_16x16x32_bf16(a, b, acc2[nt], 0, 0, 0);
        }
    }
    // ---- epilogue2: bias, store h0h (fp16) and hs = dinv*h0 (fp16) ----
#pragma unroll
    for (int nt = 0; nt < 4; ++nt) {
        int col = nt * 16 + lr;
        float bb = b2[col];
#pragma unroll
        for (int r = 0; r < 4; ++r) {
            int row = wave * 16 + lq * 4 + r;
            int gr = blockRow + row;
            if (gr < N) {
                float v = acc2[nt][r] + bb;
                size_t idx = (size_t)gr * 64 + col;
                h0h[idx] = (_Float16)v;
                hA[idx]  = (_Float16)(v * dinv[gr]);
            }
        }
    }
}

// ---------------- propagation: degree-ordered, 8 threads/node, 4x unroll ----------------

template <typename OUTT>
__global__ __launch_bounds__(256) void prop_kernel(
        const _Float16* __restrict__ hs, const _Float16* __restrict__ h0h,
        const float* __restrict__ dinv, const int* __restrict__ rp,
        const int* __restrict__ csr, const int* __restrict__ perm,
        OUTT* __restrict__ hout, int N) {
    int t = blockIdx.x * 256 + threadIdx.x;
    int slot = t >> 3;
    int l = t & 7;
    if (slot >= N) return;
    int i = perm[slot];
    int beg = rp[i], end = rp[i + 1];
    const _Float16* hb = hs + l * 8;
    h16x8 self = *(const h16x8*)(hb + (size_t)i * 64);
    float a[8];
#pragma unroll
    for (int j = 0; j < 8; ++j) a[j] = (float)self[j];   // self-loop term
    int e = beg;
    for (; e + 3 < end; e += 4) {
        int s0 = csr[e], s1 = csr[e + 1], s2 = csr[e + 2], s3 = csr[e + 3];
        h16x8 g0 = *(const h16x8*)(hb + (size_t)s0 * 64);
        h16x8 g1 = *(const h16x8*)(hb + (size_t)s1 * 64);
        h16x8 g2 = *(const h16x8*)(hb + (size_t)s2 * 64);
        h16x8 g3 = *(const h16x8*)(hb + (size_t)s3 * 64);
#pragma unroll
        for (int j = 0; j < 8; ++j) a[j] += (float)g0[j];
#pragma unroll
        for (int j = 0; j < 8; ++j) a[j] += (float)g1[j];
#pragma unroll
        for (int j = 0; j < 8; ++j) a[j] += (float)g2[j];
#pragma unroll
        for (int j = 0; j < 8; ++j) a[j] += (float)g3[j];
    }
    for (; e < end; ++e) {
        int s0 = csr[e];
        h16x8 g0 = *(const h16x8*)(hb + (size_t)s0 * 64);
#pragma unroll
        for (int j = 0; j < 8; ++j) a[j] += (float)g0[j];
    }
    float dv = dinv[i];
    float c1 = 0.9f * dv;
    const _Float16* h0p = h0h + (size_t)i * 64 + l * 8;
    h16x8 h0v = *(const h16x8*)h0p;
    float o[8];
#pragma unroll
    for (int j = 0; j < 8; ++j) o[j] = fmaf(c1, a[j], 0.1f * (float)h0v[j]);
    if constexpr (sizeof(OUTT) == 2) {
        h16x8 ov;
#pragma unroll
        for (int j = 0; j < 8; ++j) ov[j] = (_Float16)(dv * o[j]);   // store hs_new
        *(h16x8*)(hout + (size_t)i * 64 + l * 8) = ov;
    } else {
        float4* q = (float4*)(hout + (size_t)i * 64 + l * 8);
        q[0] = make_float4(o[0], o[1], o[2], o[3]);
        q[1] = make_float4(o[4], o[5], o[6], o[7]);
    }
}

// ---------------- launch ----------------

extern "C" void kernel_launch(void* const* d_in, const int* in_sizes, int n_in,
                              void* d_out, int out_size, void* d_ws, size_t ws_size,
                              hipStream_t stream) {
    const float* x  = (const float*)d_in[0];
    const int*   ei = (const int*)d_in[1];
    const float* W1 = (const float*)d_in[2];
    const float* b1 = (const float*)d_in[3];
    const float* W2 = (const float*)d_in[4];
    const float* b2 = (const float*)d_in[5];
    const int N = in_sizes[0] / 512;
    const int E = in_sizes[1] / 2;
    const int NB = (N + 63) / 64;
    const int* src = ei;
    const int* dst = ei + E;

    char* w = (char*)d_ws;
    size_t off = 0;
    auto alloc = [&](size_t bytes) -> char* {
        char* p = w + off;
        off = (off + bytes + 1023) & ~(size_t)1023;
        return p;
    };
    int*      gcur  = (int*)alloc((size_t)NB * 4);
    int*      bbase = (int*)alloc((size_t)NB * 4);
    int*      rp    = (int*)alloc(((size_t)N + 1) * 4);
    float*    dinv  = (float*)alloc((size_t)N * 4);
    int*      csr   = (int*)alloc((size_t)E * 4);
    u32*      binned= (u32*)alloc((size_t)NB * CAP * 4);
    u16*      W1t   = (u16*)alloc(512 * 256 * 2);
    u16*      W2t   = (u16*)alloc(256 * 64 * 2);
    _Float16* h0h   = (_Float16*)alloc((size_t)N * 64 * 2);
    _Float16* hA    = (_Float16*)alloc((size_t)N * 64 * 2);
    _Float16* hB    = (_Float16*)alloc((size_t)N * 64 * 2);
    int*      perm  = (int*)alloc((size_t)N * 4);
    int*      dhist = (int*)alloc(128 * 4);
    int*      dcur  = (int*)alloc(128 * 4);

    hipMemsetAsync(gcur, 0, (size_t)NB * 4, stream);
    hipMemsetAsync(dhist, 0, 128 * 4, stream);
    binscat_kernel<<<(E + EPB - 1) / EPB, 256, 0, stream>>>(src, dst, gcur, binned, E, NB);
    bucket_scan_kernel<<<1, 256, 0, stream>>>(gcur, bbase, rp, N, NB);
    buildcsr_kernel<<<NB, 256, 0, stream>>>(binned, gcur, bbase, rp, dinv, csr, dhist, N);
    dscan_kernel<<<1, 128, 0, stream>>>(dhist, dcur);
    dplace_kernel<<<(N + 255) / 256, 256, 0, stream>>>(rp, dcur, perm, N);
    prepw1_kernel<<<512, 256, 0, stream>>>(W1, W1t);
    prepw2_kernel<<<64, 256, 0, stream>>>(W2, W2t);
    mlp_kernel<<<(N + 63) / 64, 256, 0, stream>>>(x, W1t, b1, W2t, b2, dinv, h0h, hA, N);

    const _Float16* pin = hA;
    int grid = (N * 8 + 255) / 256;
    for (int it = 0; it < 9; ++it) {
        _Float16* pout = (it & 1) ? hA : hB;
        prop_kernel<_Float16><<<grid, 256, 0, stream>>>(pin, h0h, dinv, rp, csr, perm, pout, N);
        pin = pout;
    }
    prop_kernel<float><<<grid, 256, 0, stream>>>(pin, h0h, dinv, rp, csr, perm, (float*)d_out, N);
}